// Round 1
// baseline (704.471 us; speedup 1.0000x reference)
//
#include <hip/hip_runtime.h>

// Problem constants (from reference):
constexpr int B     = 32;
constexpr int N_ST  = 8;
constexpr int N_SUB = 256;
constexpr int WIN   = 2048;

// Tile: 64 w x 64 s per block, 256 threads.
constexpr int TW  = 64;
constexpr int TS  = 64;
constexpr int PAD = 65;   // 64+1: scalar LDS r/w land 2-way (free) on 32 banks

__global__ __launch_bounds__(256)
void station_agg_kernel(const float* __restrict__ schedule,  // [B, WIN, N_ST]
                        const float* __restrict__ csi,       // [B, N_ST, N_SUB, WIN]
                        float* __restrict__ out)             // [B, WIN, N_SUB]
{
    __shared__ float sched_t[N_ST][TW];   // [t][w] transposed schedule tile
    __shared__ float tile[TW * PAD];      // [w][s] padded transpose buffer

    const int s0 = blockIdx.x * TS;
    const int w0 = blockIdx.y * TW;
    const int b  = blockIdx.z;
    const int k  = threadIdx.x;           // 0..255

    // Stage schedule[b, w0..w0+63, 0..7] — one contiguous 512-float chunk.
    // Transpose to [t][w] in LDS so compute reads are b128 broadcasts.
    {
        const float* sp = schedule + ((size_t)b * WIN + w0) * N_ST;
        const int e0 = k * 2;
        const float2 v = *(const float2*)(sp + e0);
        sched_t[e0 & 7][e0 >> 3]         = v.x;
        sched_t[(e0 + 1) & 7][(e0 + 1) >> 3] = v.y;
    }
    __syncthreads();

    // Compute mapping: thread owns 4 consecutive w (one float4) x 4 s-rows.
    const int w4   = k & 15;   // float4 index along w: w = w4*4 .. w4*4+3
    const int srow = k >> 4;   // s row 0..15; rows srow + 16*m, m=0..3

    float4 acc[4];
#pragma unroll
    for (int m = 0; m < 4; ++m) acc[m] = make_float4(0.f, 0.f, 0.f, 0.f);

    const size_t base_b = (size_t)b * N_ST * N_SUB * WIN;
#pragma unroll
    for (int t = 0; t < N_ST; ++t) {
        // Per-wave: lanes with same w4 broadcast; b128, conflict-free.
        const float4 sv = *(const float4*)&sched_t[t][w4 * 4];
        const float* cp = csi + base_b
                        + ((size_t)t * N_SUB + (s0 + srow)) * WIN
                        + (w0 + w4 * 4);
#pragma unroll
        for (int m = 0; m < 4; ++m) {
            // 16 lanes/row read a contiguous 256B segment — fully coalesced.
            const float4 c = *(const float4*)(cp + (size_t)(16 * m) * WIN);
            acc[m].x += c.x * sv.x;
            acc[m].y += c.y * sv.y;
            acc[m].z += c.z * sv.z;
            acc[m].w += c.w * sv.w;
        }
    }

    // Transpose through LDS: tile[w][s], pad 65 -> 2-way bank aliasing (free).
#pragma unroll
    for (int m = 0; m < 4; ++m) {
        const int s = srow + 16 * m;
        tile[(w4 * 4 + 0) * PAD + s] = acc[m].x;
        tile[(w4 * 4 + 1) * PAD + s] = acc[m].y;
        tile[(w4 * 4 + 2) * PAD + s] = acc[m].z;
        tile[(w4 * 4 + 3) * PAD + s] = acc[m].w;
    }
    __syncthreads();

    // Coalesced float4 stores along s: out[b, w0+w, s0 + 4*s4 ..].
    const int s4 = k & 15;
    const int wr = k >> 4;
#pragma unroll
    for (int m2 = 0; m2 < 4; ++m2) {
        const int w = wr + 16 * m2;
        float4 o;
        o.x = tile[w * PAD + s4 * 4 + 0];
        o.y = tile[w * PAD + s4 * 4 + 1];
        o.z = tile[w * PAD + s4 * 4 + 2];
        o.w = tile[w * PAD + s4 * 4 + 3];
        *(float4*)(out + ((size_t)b * WIN + (w0 + w)) * N_SUB + (s0 + s4 * 4)) = o;
    }
}

extern "C" void kernel_launch(void* const* d_in, const int* in_sizes, int n_in,
                              void* d_out, int out_size, void* d_ws, size_t ws_size,
                              hipStream_t stream) {
    const float* schedule = (const float*)d_in[0];  // [B, WIN, N_ST]
    const float* csi      = (const float*)d_in[1];  // [B, N_ST, N_SUB, WIN]
    float* out            = (float*)d_out;          // [B, WIN, N_SUB]

    dim3 grid(N_SUB / TS, WIN / TW, B);   // 4 x 32 x 32 = 4096 blocks
    dim3 block(256);
    station_agg_kernel<<<grid, block, 0, stream>>>(schedule, csi, out);
}

// Round 2
// 669.813 us; speedup vs baseline: 1.0517x; 1.0517x over previous
//
#include <hip/hip_runtime.h>

// Problem constants (from reference):
constexpr int B     = 32;
constexpr int N_ST  = 8;
constexpr int N_SUB = 256;
constexpr int WIN   = 2048;

// Tile: 256 w x 16 s per block, 256 threads (4 waves).
// Every wave csi load = one contiguous 1 KB segment (64 lanes x float4).
constexpr int TW  = 256;
constexpr int TS  = 16;
constexpr int STR = 260;   // tile2 row stride (floats): 256+4 keeps float4
                           // alignment; epilogue scalar reads land 2-way (free)

typedef float f4 __attribute__((ext_vector_type(4)));

__global__ __launch_bounds__(256)
void station_agg_kernel(const float* __restrict__ schedule,  // [B, WIN, N_ST]
                        const float* __restrict__ csi,       // [B, N_ST, N_SUB, WIN]
                        float* __restrict__ out)             // [B, WIN, N_SUB]
{
    __shared__ float sched_t[N_ST][TW];   // 8 KB   [t][w] transposed schedule
    __shared__ float tile2[TS * STR];     // 16.6KB [s][w+pad] transpose buffer

    const int s0 = blockIdx.x * TS;
    const int w0 = blockIdx.y * TW;
    const int b  = blockIdx.z;
    const int k  = threadIdx.x;           // 0..255
    const int wv = k >> 6;                // wave 0..3
    const int l  = k & 63;                // lane 0..63

    // Stage schedule[b, w0..w0+255, 0..7] transposed -> sched_t[t][w].
    // Thread k loads w-row k's 8 weights (two float4s, 32 B aligned).
    {
        const float* sp = schedule + ((size_t)b * WIN + w0 + k) * N_ST;
        const f4 a = *(const f4*)sp;
        const f4 c = *(const f4*)(sp + 4);
        sched_t[0][k] = a.x; sched_t[1][k] = a.y;
        sched_t[2][k] = a.z; sched_t[3][k] = a.w;
        sched_t[4][k] = c.x; sched_t[5][k] = c.y;
        sched_t[6][k] = c.z; sched_t[7][k] = c.w;
    }
    __syncthreads();

    // Wave wv owns s rows s0+4*wv+j (j=0..3); lane l owns w = w0+4l..4l+3.
    f4 acc[4];
#pragma unroll
    for (int j = 0; j < 4; ++j) acc[j] = (f4)(0.0f);

    const size_t bbase = (size_t)b * N_ST * N_SUB * WIN;
#pragma unroll
    for (int t = 0; t < N_ST; ++t) {
        // b128 LDS read, lanes 16B-contiguous -> conflict-free.
        const f4 sv = *(const f4*)&sched_t[t][4 * l];
        const float* cp = csi + bbase
                        + ((size_t)t * N_SUB + (s0 + 4 * wv)) * WIN
                        + (w0 + 4 * l);
#pragma unroll
        for (int j = 0; j < 4; ++j) {
            // One contiguous 1 KB segment per wave instruction; csi is
            // read-once (537 MB) -> nontemporal, don't pollute L2.
            const f4 c = __builtin_nontemporal_load((const f4*)(cp + (size_t)j * WIN));
            acc[j] += c * sv;
        }
    }

    // Transpose via LDS: tile2[s][w], b128 writes lanes-contiguous -> 0-conflict.
#pragma unroll
    for (int j = 0; j < 4; ++j)
        *(f4*)&tile2[(4 * wv + j) * STR + 4 * l] = acc[j];
    __syncthreads();

    // Coalesced out stores: per wave instr, 16 w-rows x 16 s = 16 aligned
    // 64B lines. Epilogue LDS reads: 2-way bank aliasing (free).
#pragma unroll
    for (int m = 0; m < 4; ++m) {
        const int wrow = 16 * wv + (l >> 2) + 64 * m;  // 0..255
        const int sl   = 4 * (l & 3);                  // 0,4,8,12
        f4 o;
        o.x = tile2[(sl + 0) * STR + wrow];
        o.y = tile2[(sl + 1) * STR + wrow];
        o.z = tile2[(sl + 2) * STR + wrow];
        o.w = tile2[(sl + 3) * STR + wrow];
        __builtin_nontemporal_store(o,
            (f4*)(out + ((size_t)b * WIN + (w0 + wrow)) * N_SUB + (s0 + sl)));
    }
}

extern "C" void kernel_launch(void* const* d_in, const int* in_sizes, int n_in,
                              void* d_out, int out_size, void* d_ws, size_t ws_size,
                              hipStream_t stream) {
    const float* schedule = (const float*)d_in[0];  // [B, WIN, N_ST]
    const float* csi      = (const float*)d_in[1];  // [B, N_ST, N_SUB, WIN]
    float* out            = (float*)d_out;          // [B, WIN, N_SUB]

    dim3 grid(N_SUB / TS, WIN / TW, B);   // 16 x 8 x 32 = 4096 blocks
    dim3 block(256);
    station_agg_kernel<<<grid, block, 0, stream>>>(schedule, csi, out);
}